// Round 6
// baseline (434.754 us; speedup 1.0000x reference)
//
#include <hip/hip_runtime.h>
#include <hip/hip_cooperative_groups.h>

namespace cg = cooperative_groups;

#define NPOS 16384
#define NEG  (-1e30f)

// workspace offsets (floats)
#define OFF_FWDH  0
#define OFF_BWDH  1966080
#define OFF_A     3932160
#define OFF_T0    4194304
#define OFF_R     4251904
#define OFF_GSC   4255504

#define SMEM_A 28480

struct Params {
    const float *data, *fWih, *fWhh, *fbih, *fbhh, *bWih, *bWhh, *bbih, *bbhh;
    const float *h0f, *c0f, *h0b, *c0b, *Yenc, *Zenc, *VW, *Vb, *WW, *Wb;
    const int *tags, *lengths;
    float *ws; float *out;
};

__device__ __forceinline__ float sigf(float x) {
    return __builtin_amdgcn_rcpf(1.0f + __expf(-x));
}
__device__ __forceinline__ float tanhf_(float x) {
    return 1.0f - 2.0f * __builtin_amdgcn_rcpf(1.0f + __expf(2.0f * x));
}
__device__ __forceinline__ float bf2f(unsigned short u) {
    unsigned int v = ((unsigned int)u) << 16;
    return __builtin_bit_cast(float, v);
}
__device__ __forceinline__ unsigned short f2bf(float f) {
    unsigned int b = __builtin_bit_cast(unsigned int, f);
    return (unsigned short)((b + 0x8000u) >> 16);
}
__device__ __forceinline__ float lse15(const float* tv) {
    float a0 = fmaxf(tv[0], tv[1]),  a1 = fmaxf(tv[2], tv[3]);
    float a2 = fmaxf(tv[4], tv[5]),  a3 = fmaxf(tv[6], tv[7]);
    float a4 = fmaxf(tv[8], tv[9]),  a5 = fmaxf(tv[10], tv[11]);
    float a6 = fmaxf(tv[12], tv[13]);
    float b0 = fmaxf(a0, a1), b1 = fmaxf(a2, a3), b2 = fmaxf(a4, a5), b3 = fmaxf(a6, tv[14]);
    float mx = fmaxf(fmaxf(b0, b1), fmaxf(b2, b3));
    float e[15];
    #pragma unroll
    for (int i = 0; i < 15; i++) e[i] = __expf(tv[i] - mx);
    float s0 = e[0]+e[1], s1 = e[2]+e[3], s2 = e[4]+e[5], s3 = e[6]+e[7];
    float s4 = e[8]+e[9], s5 = e[10]+e[11], s6 = e[12]+e[13];
    float t0 = s0+s1, t1 = s2+s3, t2 = s4+s5, t3 = s6+e[14];
    return mx + __logf((t0+t1) + (t2+t3));
}

// ================= Phase A: xg + LSTM (one dir, one 64-pos chunk; 512 thr) ==
// Weights read from global with wave-uniform indices (s_load / constant cache).
// LDS: xs bf16 [78][33]u32 (10304) + xgT [32][78]u32 (9984) + hsh 2x1024 f32 (8192)
__device__ __forceinline__ void phaseA(const Params& p, char* smem, int tid,
                                       int chunk, int dir)
{
    const int lane = tid & 63;
    const int wq   = __builtin_amdgcn_readfirstlane(tid >> 6);
    const int P0   = chunk << 6;
    const int dbase = P0 - (dir ? 14 : 0);
    unsigned int* xs2 = (unsigned int*)smem;             // [78][33]
    unsigned int* xgT = (unsigned int*)(smem + 10304);   // [32][78]
    float*        hsh = (float*)(smem + 10304 + 9984);   // [2][1024]

    const float* Wih = dir ? p.bWih : p.fWih;
    const float* Whh = dir ? p.bWhh : p.fWhh;
    const float* bih = dir ? p.bbih : p.fbih;
    const float* bhh = dir ? p.bbhh : p.fbhh;
    const float* h0  = dir ? p.h0b  : p.h0f;
    const float* c0  = dir ? p.c0b  : p.c0f;

    int jrow[8];   // wave-uniform logical gate rows (i,i, f,f, g,g, o,o for 2 units)
    #pragma unroll
    for (int jj = 0; jj < 8; jj++) jrow[jj] = ((jj >> 1) << 4) + 2*wq + (jj & 1);

    for (int idx = tid; idx < 78*32; idx += 512) {
        int r = idx >> 5, c = idx & 31;
        int q = dbase + r;
        q = q < 0 ? 0 : (q > NPOS-1 ? NPOS-1 : q);
        float2 x2 = *(const float2*)(p.data + (size_t)q*64 + c*2);
        xs2[r*33 + c] = (unsigned int)f2bf(x2.x) | ((unsigned int)f2bf(x2.y) << 16);
    }
    for (int e = tid; e < 1024; e += 512) hsh[e] = h0[e >> 6];
    __syncthreads();

    // xg = x @ Wih^T + b for rows 0..77, packed bf16 into xgT
    #pragma unroll
    for (int pass = 0; pass < 2; pass++) {
        int r = pass*64 + lane;
        if (r < 78) {
            float acc[8];
            #pragma unroll
            for (int jj = 0; jj < 8; jj++) acc[jj] = bih[jrow[jj]] + bhh[jrow[jj]];
            #pragma unroll 4
            for (int k2 = 0; k2 < 32; k2++) {
                unsigned int v = xs2[r*33 + k2];
                float x0 = bf2f((unsigned short)(v & 0xffff));
                float x1 = bf2f((unsigned short)(v >> 16));
                #pragma unroll
                for (int jj = 0; jj < 8; jj++) {
                    acc[jj] = fmaf(Wih[jrow[jj]*64 + 2*k2],     x0, acc[jj]);
                    acc[jj] = fmaf(Wih[jrow[jj]*64 + 2*k2 + 1], x1, acc[jj]);
                }
            }
            #pragma unroll
            for (int g2 = 0; g2 < 4; g2++)
                xgT[(wq*4 + g2)*78 + r] = (unsigned int)f2bf(acc[2*g2])
                                        | ((unsigned int)f2bf(acc[2*g2+1]) << 16);
        }
    }
    float cv0 = c0[wq*2], cv1 = c0[wq*2 + 1];
    unsigned int* outH = (unsigned int*)(p.ws + (dir ? OFF_BWDH : OFF_FWDH));
    __syncthreads();

    int buf = 0;
    for (int d = 0; d < 15; d++) {
        const int row = dir ? (lane + 14 - d) : (lane + d);
        float part[8];
        #pragma unroll
        for (int g2 = 0; g2 < 4; g2++) {
            unsigned int v = xgT[(wq*4 + g2)*78 + row];
            part[2*g2]   = bf2f((unsigned short)(v & 0xffff));
            part[2*g2+1] = bf2f((unsigned short)(v >> 16));
        }
        #pragma unroll
        for (int m = 0; m < 16; m++) {
            float hm = hsh[buf*1024 + m*64 + lane];
            #pragma unroll
            for (int jj = 0; jj < 8; jj++)
                part[jj] = fmaf(Whh[jrow[jj]*16 + m], hm, part[jj]);
        }
        float cn0 = sigf(part[2])*cv0 + sigf(part[0])*tanhf_(part[4]);
        float cn1 = sigf(part[3])*cv1 + sigf(part[1])*tanhf_(part[5]);
        cv0 = cn0; cv1 = cn1;
        float h0v = sigf(part[6])*tanhf_(cn0);
        float h1v = sigf(part[7])*tanhf_(cn1);
        hsh[(buf^1)*1024 + (wq*2)*64 + lane]     = h0v;
        hsh[(buf^1)*1024 + (wq*2 + 1)*64 + lane] = h1v;
        unsigned int pk = (unsigned int)f2bf(h0v) | ((unsigned int)f2bf(h1v) << 16);
        outH[((size_t)d*NPOS + P0 + lane)*8 + wq] = pk;
        __syncthreads();
        buf ^= 1;
    }
}

// ================= Phase B: scores + A (thread = element g) ==================
__device__ __forceinline__ void phaseB(const Params& p, char* smem, int tid, int g)
{
    float* yp2 = (float*)smem;          // 240
    float* zbl = (float*)smem + 240;    // 240
    if (tid < 240) {
        int y = tid >> 4, h = tid & 15;
        float acc = 0.f;
        for (int t = 0; t < 32; t++) acc += p.Yenc[y*32 + t] * p.VW[h*68 + 32 + t];
        yp2[tid] = 2.0f * acc;
        float z = p.Vb[h];
        for (int u = 0; u < 4; u++) z += p.Zenc[y*4 + u] * p.VW[h*68 + 64 + u];
        zbl[tid] = z;
    }
    __syncthreads();
    const int pp  = g & (NPOS - 1);
    const int dgl = g >> 14;
    float* ws = p.ws;
    float* A16 = ws + OFF_A;
    if (dgl >= 15) return;
    if (dgl == 0) A16[pp*16 + 15] = NEG;
    if (pp < dgl) { A16[pp*16 + dgl] = NEG; return; }

    const uint4* fptr = (const uint4*)((const unsigned short*)(ws + OFF_FWDH)
                        + ((size_t)dgl*NPOS + (pp - dgl))*16);
    const uint4* bptr = (const uint4*)((const unsigned short*)(ws + OFF_BWDH)
                        + ((size_t)dgl*NPOS + pp)*16);
    float fb0[16], fb1[16];
    #pragma unroll
    for (int q = 0; q < 2; q++) {
        uint4 v = fptr[q];
        unsigned int wv4[4] = {v.x, v.y, v.z, v.w};
        #pragma unroll
        for (int t = 0; t < 4; t++) {
            fb0[q*8 + 2*t]     = bf2f((unsigned short)(wv4[t] & 0xffff));
            fb0[q*8 + 2*t + 1] = bf2f((unsigned short)(wv4[t] >> 16));
        }
        uint4 u = bptr[q];
        unsigned int uu[4] = {u.x, u.y, u.z, u.w};
        #pragma unroll
        for (int t = 0; t < 4; t++) {
            fb1[q*8 + 2*t]     = bf2f((unsigned short)(uu[t] & 0xffff));
            fb1[q*8 + 2*t + 1] = bf2f((unsigned short)(uu[t] >> 16));
        }
    }
    float base2[16], w2[16], wsum = 0.f;
    #pragma unroll
    for (int h = 0; h < 16; h++) {
        float acc = zbl[dgl*16 + h];
        #pragma unroll
        for (int m = 0; m < 16; m++) acc = fmaf(p.VW[h*68 + m],      fb0[m], acc);
        #pragma unroll
        for (int m = 0; m < 16; m++) acc = fmaf(p.VW[h*68 + 16 + m], fb1[m], acc);
        base2[h] = acc + acc;
        float w = p.WW[h];
        w2[h] = -2.0f * w;
        wsum += w;
    }
    const float cst = p.Wb[0] + wsum;
    float sc[15];
    #pragma unroll
    for (int y = 0; y < 15; y++) {
        float a = 0.f;
        #pragma unroll
        for (int h = 0; h < 16; h++) {
            float t = __expf(base2[h] + yp2[y*16 + h]);
            a = fmaf(w2[h], __builtin_amdgcn_rcpf(1.0f + t), a);
        }
        sc[y] = cst + a;
    }
    A16[pp*16 + dgl] = lse15(sc);
    if (pp == dgl && pp < 15) {
        float* gsc = ws + OFF_GSC;
        #pragma unroll
        for (int y = 0; y < 15; y++) gsc[pp*15 + y] = sc[y];
    }
}

// ================= Phase C: chunk transfer matrices (64 steps) ===============
__device__ __forceinline__ void phaseC(const Params& p, char* smem, int tid, int chunk)
{
    float* la = (float*)smem;   // 1024
    const float* Ab = p.ws + OFF_A + (size_t)chunk * 1024;
    for (int idx = tid; idx < 1024; idx += 512) la[idx] = Ab[idx];
    __syncthreads();
    if (tid < 15) {
        const int j = tid;
        float s[15];
        #pragma unroll
        for (int i = 0; i < 15; i++) s[i] = (i == j) ? 0.f : NEG;
        #pragma unroll 4
        for (int t = 0; t < 64; t++) {
            float tv[15];
            #pragma unroll
            for (int i = 0; i < 15; i++) tv[i] = s[i] + la[t*16 + i];
            float nw = lse15(tv);
            #pragma unroll
            for (int i = 14; i > 0; i--) s[i] = s[i-1];
            s[0] = nw;
        }
        float* T0 = p.ws + OFF_T0;
        #pragma unroll
        for (int i = 0; i < 15; i++) T0[chunk*225 + i*15 + j] = s[i];
    }
}

// ================= Phase D: combine 16 chunk matrices ========================
__device__ __forceinline__ void phaseD(const Params& p, char* smem, int tid, int b)
{
    float* Rm = (float*)smem;   // 240, stride 16
    const float* T0 = p.ws + OFF_T0;
    const int e = tid, i2 = e / 15, j2 = e % 15;
    const int c0 = b * 16;
    if (e < 225) Rm[i2*16 + j2] = T0[c0*225 + e];
    __syncthreads();
    for (int t = 1; t < 16; t++) {
        float nw = 0.f;
        if (e < 225) {
            const float* Trow = T0 + (c0 + t)*225 + i2*15;
            float tv[15];
            #pragma unroll
            for (int k = 0; k < 15; k++) tv[k] = Trow[k] + Rm[k*16 + j2];
            nw = lse15(tv);
        }
        __syncthreads();
        if (e < 225) Rm[i2*16 + j2] = nw;
        __syncthreads();
    }
    if (e < 225) p.ws[OFF_R + b*225 + e] = Rm[i2*16 + j2];
}

// ================= Phase E: final combine + indiv + out ======================
__device__ __forceinline__ void phaseE(const Params& p, char* smem, int tid)
{
    float* RA  = (float*)smem;           // 16*240
    float* G   = (float*)smem + 3840;    // 240
    float* red = (float*)smem + 4080;    // 8
    const float* Rg = p.ws + OFF_R;
    for (int idx = tid; idx < 16*225; idx += 512) {
        int t = idx / 225, r = idx % 225;
        RA[t*240 + (r/15)*16 + (r%15)] = Rg[idx];
    }
    __syncthreads();
    const int e = tid, i2 = e / 15, j2 = e % 15;
    if (e < 225) G[i2*16 + j2] = RA[i2*16 + j2];
    __syncthreads();
    for (int t = 1; t < 16; t++) {
        float nw = 0.f;
        if (e < 225) {
            float tv[15];
            #pragma unroll
            for (int k = 0; k < 15; k++) tv[k] = RA[t*240 + i2*16 + k] + G[k*16 + j2];
            nw = lse15(tv);
        }
        __syncthreads();
        if (e < 225) G[i2*16 + j2] = nw;
        __syncthreads();
    }
    const float* gsc = p.ws + OFF_GSC;
    float loc = 0.f;
    for (int s = tid; s < 2048; s += 512) {
        int len = p.lengths[s];
        if (len < 15) loc += gsc[(len-1)*15 + p.tags[s]];
    }
    #pragma unroll
    for (int off = 32; off > 0; off >>= 1) loc += __shfl_down(loc, off);
    if ((tid & 63) == 0) red[tid >> 6] = loc;
    __syncthreads();
    if (tid == 0) {
        float ind = 0.f;
        #pragma unroll
        for (int w = 0; w < 8; w++) ind += red[w];
        p.out[0] = G[0] - ind;
    }
}

// ================= Cooperative mega-kernel ==================================
__global__ __launch_bounds__(512, 4) void k_mega(Params p)
{
    __shared__ char smem[SMEM_A];
    cg::grid_group grid = cg::this_grid();
    const int tid = threadIdx.x;
    const int bid = blockIdx.x;

    phaseA(p, smem, tid, bid & 255, bid >> 8);
    grid.sync();
    phaseB(p, smem, tid, bid*512 + tid);
    grid.sync();
    if (bid < 256) phaseC(p, smem, tid, bid);
    grid.sync();
    if (bid < 16) phaseD(p, smem, tid, bid);
    grid.sync();
    if (bid == 0) phaseE(p, smem, tid);
}

// ================= Fallback phase kernels ===================================
__global__ __launch_bounds__(512) void k_pA(Params p) {
    __shared__ char smem[SMEM_A];
    phaseA(p, smem, threadIdx.x, blockIdx.x, blockIdx.y);
}
__global__ __launch_bounds__(512) void k_pB(Params p) {
    __shared__ char smem[1920];
    phaseB(p, smem, threadIdx.x, blockIdx.x*512 + threadIdx.x);
}
__global__ __launch_bounds__(512) void k_pC(Params p) {
    __shared__ char smem[4096];
    phaseC(p, smem, threadIdx.x, blockIdx.x);
}
__global__ __launch_bounds__(256) void k_pD(Params p) {
    __shared__ char smem[960];
    phaseD(p, smem, threadIdx.x, blockIdx.x);
}
__global__ __launch_bounds__(512) void k_pE(Params p) {
    __shared__ char smem[16352];
    phaseE(p, smem, threadIdx.x);
}

// ================= launcher =================================================
extern "C" void kernel_launch(void* const* d_in, const int* in_sizes, int n_in,
                              void* d_out, int out_size, void* d_ws, size_t ws_size,
                              hipStream_t stream)
{
    Params prm;
    prm.data = (const float*)d_in[0];
    prm.fWih = (const float*)d_in[1];
    prm.fWhh = (const float*)d_in[2];
    prm.fbih = (const float*)d_in[3];
    prm.fbhh = (const float*)d_in[4];
    prm.bWih = (const float*)d_in[5];
    prm.bWhh = (const float*)d_in[6];
    prm.bbih = (const float*)d_in[7];
    prm.bbhh = (const float*)d_in[8];
    prm.h0f  = (const float*)d_in[9];
    prm.c0f  = (const float*)d_in[10];
    prm.h0b  = (const float*)d_in[11];
    prm.c0b  = (const float*)d_in[12];
    prm.Yenc = (const float*)d_in[13];
    prm.Zenc = (const float*)d_in[14];
    prm.VW   = (const float*)d_in[15];
    prm.Vb   = (const float*)d_in[16];
    prm.WW   = (const float*)d_in[17];
    prm.Wb   = (const float*)d_in[18];
    prm.tags    = (const int*)d_in[19];
    prm.lengths = (const int*)d_in[20];
    prm.ws  = (float*)d_ws;
    prm.out = (float*)d_out;

    void* args[] = { &prm };
    hipError_t err = hipLaunchCooperativeKernel((const void*)k_mega,
                                                dim3(512), dim3(512),
                                                args, 0, stream);
    if (err != hipSuccess) {
        (void)hipGetLastError();   // clear sticky error; use multi-kernel path
        hipLaunchKernelGGL(k_pA, dim3(256, 2), dim3(512), 0, stream, prm);
        hipLaunchKernelGGL(k_pB, dim3(512), dim3(512), 0, stream, prm);
        hipLaunchKernelGGL(k_pC, dim3(256), dim3(512), 0, stream, prm);
        hipLaunchKernelGGL(k_pD, dim3(16), dim3(256), 0, stream, prm);
        hipLaunchKernelGGL(k_pE, dim3(1), dim3(512), 0, stream, prm);
    }
}

// Round 7
// 251.450 us; speedup vs baseline: 1.7290x; 1.7290x over previous
//
#include <hip/hip_runtime.h>

#define NPOS 16384
#define NEG  (-1e30f)

// workspace offsets (floats)
#define OFF_FWDH  0
#define OFF_BWDH  1966080
#define OFF_A     3932160
#define OFF_T0    4194304
#define OFF_R     4251904
#define OFF_GSC   4255504
#define OFF_CTR   4255744   // 2 x u32

struct Params {
    const float *data, *fWih, *fWhh, *fbih, *fbhh, *bWih, *bWhh, *bbih, *bbhh;
    const float *h0f, *c0f, *h0b, *c0b, *Yenc, *Zenc, *VW, *Vb, *WW, *Wb;
    const int *tags, *lengths;
    float *ws; float *out;
};

__device__ __forceinline__ float sigf(float x) {
    return __builtin_amdgcn_rcpf(1.0f + __expf(-x));
}
__device__ __forceinline__ float tanhf_(float x) {
    return 1.0f - 2.0f * __builtin_amdgcn_rcpf(1.0f + __expf(2.0f * x));
}
__device__ __forceinline__ float bf2f(unsigned short u) {
    unsigned int v = ((unsigned int)u) << 16;
    return __builtin_bit_cast(float, v);
}
__device__ __forceinline__ float bflo(unsigned int v) {
    return __builtin_bit_cast(float, v << 16);
}
__device__ __forceinline__ float bfhi(unsigned int v) {
    return __builtin_bit_cast(float, v & 0xffff0000u);
}
__device__ __forceinline__ unsigned short f2bf(float f) {
    unsigned int b = __builtin_bit_cast(unsigned int, f);
    return (unsigned short)((b + 0x8000u) >> 16);
}
__device__ __forceinline__ float lse15(const float* tv) {
    float a0 = fmaxf(tv[0], tv[1]),  a1 = fmaxf(tv[2], tv[3]);
    float a2 = fmaxf(tv[4], tv[5]),  a3 = fmaxf(tv[6], tv[7]);
    float a4 = fmaxf(tv[8], tv[9]),  a5 = fmaxf(tv[10], tv[11]);
    float a6 = fmaxf(tv[12], tv[13]);
    float b0 = fmaxf(a0, a1), b1 = fmaxf(a2, a3), b2 = fmaxf(a4, a5), b3 = fmaxf(a6, tv[14]);
    float mx = fmaxf(fmaxf(b0, b1), fmaxf(b2, b3));
    float e[15];
    #pragma unroll
    for (int i = 0; i < 15; i++) e[i] = __expf(tv[i] - mx);
    float s0 = e[0]+e[1], s1 = e[2]+e[3], s2 = e[4]+e[5], s3 = e[6]+e[7];
    float s4 = e[8]+e[9], s5 = e[10]+e[11], s6 = e[12]+e[13];
    float t0 = s0+s1, t1 = s2+s3, t2 = s4+s5, t3 = s6+e[14];
    return mx + __logf((t0+t1) + (t2+t3));
}

// ================= kA: pack weights (bf16, LDS) + xg + LSTM =================
// grid (256, 2): blockIdx.y = dir. 512 thr = 8 waves; wave wq owns hidden
// units {2wq, 2wq+1} (gates i,f,g,o). lane = position.
__global__ __launch_bounds__(512) void kA(Params p)
{
    __shared__ unsigned int xs2[78*33];   // x rows bf16-pair, stride 33 (10296 B)
    __shared__ unsigned int xgT[32*78];   // xg bf16-pair [gatepair][row] (9984 B)
    __shared__ float hsh[2048];           // h double-buffer (8192 B)
    __shared__ uint4 wqxq[512];           // Wih packed: [k][wq] 8 bf16 (8192 B)
    __shared__ uint4 wqhq[128];           // Whh packed: [m][wq] 8 bf16 (2048 B)
    __shared__ float bq[64];

    const int tid  = threadIdx.x;
    const int lane = tid & 63;
    const int wq   = __builtin_amdgcn_readfirstlane(tid >> 6);
    const int dir  = blockIdx.y;
    const int P0   = blockIdx.x << 6;
    const int dbase = P0 - (dir ? 14 : 0);

    if (blockIdx.x == 0 && dir == 0 && tid == 0) {
        unsigned int* ctr = (unsigned int*)(p.ws + OFF_CTR);
        ctr[0] = 0; ctr[1] = 0;
    }

    const float* Wih = dir ? p.bWih : p.fWih;
    const float* Whh = dir ? p.bWhh : p.fWhh;
    const float* bih = dir ? p.bbih : p.fbih;
    const float* bhh = dir ? p.bbhh : p.fbhh;
    const float* h0  = dir ? p.h0b  : p.h0f;
    const float* c0  = dir ? p.c0b  : p.c0f;

    // pack Wih: entry e=(k,pi): pi=w*4+g2 -> gates j0=g2*16+2w, j0+1
    unsigned int* wqx = (unsigned int*)wqxq;
    unsigned int* wqh = (unsigned int*)wqhq;
    for (int e = tid; e < 2048; e += 512) {
        int k = e >> 5, pi = e & 31;
        int w = pi >> 2, g2 = pi & 3;
        int j0 = g2*16 + 2*w;
        wqx[e] = (unsigned int)f2bf(Wih[j0*64 + k])
               | ((unsigned int)f2bf(Wih[(j0+1)*64 + k]) << 16);
    }
    if (tid < 512) {
        int e = tid;
        int m = e >> 5, pi = e & 31;
        int w = pi >> 2, g2 = pi & 3;
        int j0 = g2*16 + 2*w;
        wqh[e] = (unsigned int)f2bf(Whh[j0*16 + m])
               | ((unsigned int)f2bf(Whh[(j0+1)*16 + m]) << 16);
    }
    if (tid < 64) {
        int w = tid >> 3, jj = tid & 7;
        int j = ((jj >> 1) << 4) + 2*w + (jj & 1);
        bq[tid] = bih[j] + bhh[j];
    }
    for (int idx = tid; idx < 78*32; idx += 512) {
        int r = idx >> 5, c = idx & 31;
        int q = dbase + r;
        q = q < 0 ? 0 : (q > NPOS-1 ? NPOS-1 : q);
        float2 x2 = *(const float2*)(p.data + (size_t)q*64 + c*2);
        xs2[r*33 + c] = (unsigned int)f2bf(x2.x) | ((unsigned int)f2bf(x2.y) << 16);
    }
    for (int e = tid; e < 1024; e += 512) hsh[e] = h0[e >> 6];
    __syncthreads();

    // xg = x @ Wih^T + b for rows 0..77 (bf16 weights from LDS, b128 broadcast)
    #pragma unroll
    for (int pass = 0; pass < 2; pass++) {
        int r = pass*64 + lane;
        if (r < 78) {
            float acc[8];
            #pragma unroll
            for (int jj = 0; jj < 8; jj++) acc[jj] = bq[wq*8 + jj];
            #pragma unroll 4
            for (int k2 = 0; k2 < 32; k2++) {
                unsigned int xp = xs2[r*33 + k2];
                float x0 = bflo(xp), x1 = bfhi(xp);
                uint4 w0 = wqxq[(2*k2)*8 + wq];
                uint4 w1 = wqxq[(2*k2+1)*8 + wq];
                unsigned int wa[4] = {w0.x, w0.y, w0.z, w0.w};
                unsigned int wb[4] = {w1.x, w1.y, w1.z, w1.w};
                #pragma unroll
                for (int g2 = 0; g2 < 4; g2++) {
                    acc[2*g2]   = fmaf(bflo(wa[g2]), x0, acc[2*g2]);
                    acc[2*g2]   = fmaf(bflo(wb[g2]), x1, acc[2*g2]);
                    acc[2*g2+1] = fmaf(bfhi(wa[g2]), x0, acc[2*g2+1]);
                    acc[2*g2+1] = fmaf(bfhi(wb[g2]), x1, acc[2*g2+1]);
                }
            }
            #pragma unroll
            for (int g2 = 0; g2 < 4; g2++)
                xgT[(wq*4 + g2)*78 + r] = (unsigned int)f2bf(acc[2*g2])
                                        | ((unsigned int)f2bf(acc[2*g2+1]) << 16);
        }
    }
    float cv0 = c0[wq*2], cv1 = c0[wq*2 + 1];
    unsigned int* outH = (unsigned int*)(p.ws + (dir ? OFF_BWDH : OFF_FWDH));
    __syncthreads();

    int buf = 0;
    for (int d = 0; d < 15; d++) {
        const int row = dir ? (lane + 14 - d) : (lane + d);
        float part[8];
        #pragma unroll
        for (int g2 = 0; g2 < 4; g2++) {
            unsigned int v = xgT[(wq*4 + g2)*78 + row];
            part[2*g2]   = bflo(v);
            part[2*g2+1] = bfhi(v);
        }
        #pragma unroll
        for (int m = 0; m < 16; m++) {
            float hm = hsh[buf*1024 + m*64 + lane];
            uint4 wm = wqhq[m*8 + wq];
            unsigned int wv[4] = {wm.x, wm.y, wm.z, wm.w};
            #pragma unroll
            for (int g2 = 0; g2 < 4; g2++) {
                part[2*g2]   = fmaf(bflo(wv[g2]), hm, part[2*g2]);
                part[2*g2+1] = fmaf(bfhi(wv[g2]), hm, part[2*g2+1]);
            }
        }
        float cn0 = sigf(part[2])*cv0 + sigf(part[0])*tanhf_(part[4]);
        float cn1 = sigf(part[3])*cv1 + sigf(part[1])*tanhf_(part[5]);
        cv0 = cn0; cv1 = cn1;
        float h0v = sigf(part[6])*tanhf_(cn0);
        float h1v = sigf(part[7])*tanhf_(cn1);
        hsh[(buf^1)*1024 + (wq*2)*64 + lane]     = h0v;
        hsh[(buf^1)*1024 + (wq*2 + 1)*64 + lane] = h1v;
        unsigned int pk = (unsigned int)f2bf(h0v) | ((unsigned int)f2bf(h1v) << 16);
        outH[((size_t)d*NPOS + P0 + lane)*8 + wq] = pk;
        __syncthreads();
        buf ^= 1;
    }
}

// ================= kB: scores + A (480 blocks x 512 thr) =====================
__global__ __launch_bounds__(512) void kB(Params p)
{
    __shared__ float yp2[240];
    __shared__ float zbl[240];
    const int tid = threadIdx.x;
    if (tid < 240) {
        int y = tid >> 4, h = tid & 15;
        float acc = 0.f;
        for (int t = 0; t < 32; t++) acc += p.Yenc[y*32 + t] * p.VW[h*68 + 32 + t];
        yp2[tid] = 2.0f * acc;
        float z = p.Vb[h];
        for (int u = 0; u < 4; u++) z += p.Zenc[y*4 + u] * p.VW[h*68 + 64 + u];
        zbl[tid] = z;
    }
    __syncthreads();
    const int g   = blockIdx.x*512 + tid;
    const int pp  = g & (NPOS - 1);
    const int dgl = g >> 14;
    float* ws = p.ws;
    float* A16 = ws + OFF_A;
    if (dgl == 0) A16[pp*16 + 15] = NEG;
    if (pp < dgl) { A16[pp*16 + dgl] = NEG; return; }

    const uint4* fptr = (const uint4*)((const unsigned short*)(ws + OFF_FWDH)
                        + ((size_t)dgl*NPOS + (pp - dgl))*16);
    const uint4* bptr = (const uint4*)((const unsigned short*)(ws + OFF_BWDH)
                        + ((size_t)dgl*NPOS + pp)*16);
    float fb0[16], fb1[16];
    #pragma unroll
    for (int q = 0; q < 2; q++) {
        uint4 v = fptr[q];
        unsigned int wv4[4] = {v.x, v.y, v.z, v.w};
        #pragma unroll
        for (int t = 0; t < 4; t++) {
            fb0[q*8 + 2*t]     = bflo(wv4[t]);
            fb0[q*8 + 2*t + 1] = bfhi(wv4[t]);
        }
        uint4 u = bptr[q];
        unsigned int uu[4] = {u.x, u.y, u.z, u.w};
        #pragma unroll
        for (int t = 0; t < 4; t++) {
            fb1[q*8 + 2*t]     = bflo(uu[t]);
            fb1[q*8 + 2*t + 1] = bfhi(uu[t]);
        }
    }
    float base2[16], w2[16], wsum = 0.f;
    #pragma unroll
    for (int h = 0; h < 16; h++) {
        float acc = zbl[dgl*16 + h];
        #pragma unroll
        for (int m = 0; m < 16; m++) acc = fmaf(p.VW[h*68 + m],      fb0[m], acc);
        #pragma unroll
        for (int m = 0; m < 16; m++) acc = fmaf(p.VW[h*68 + 16 + m], fb1[m], acc);
        base2[h] = acc + acc;
        float w = p.WW[h];
        w2[h] = -2.0f * w;
        wsum += w;
    }
    const float cst = p.Wb[0] + wsum;
    float sc[15];
    #pragma unroll
    for (int y = 0; y < 15; y++) {
        float a = 0.f;
        #pragma unroll
        for (int h = 0; h < 16; h++) {
            float t = __expf(base2[h] + yp2[y*16 + h]);
            a = fmaf(w2[h], __builtin_amdgcn_rcpf(1.0f + t), a);
        }
        sc[y] = cst + a;
    }
    A16[pp*16 + dgl] = lse15(sc);
    if (pp == dgl && pp < 15) {
        float* gsc = ws + OFF_GSC;
        #pragma unroll
        for (int y = 0; y < 15; y++) gsc[pp*15 + y] = sc[y];
    }
}

// ================= kCDE: chunk DP + combine + final (one launch) =============
// 256 blocks x 256 thr, all co-resident (<= CU count). Hand-rolled barrier:
// agent-scope atomics; only blocks 0-15 (D) and block 0 (E) spin.
__global__ __launch_bounds__(256) void kCDE(Params p)
{
    __shared__ float sm[4088];
    const int tid = threadIdx.x;
    const int b   = blockIdx.x;
    unsigned int* ctr = (unsigned int*)(p.ws + OFF_CTR);

    // ---- C: 64-step chunk transfer matrix ----
    {
        float* la = sm;   // 1024
        const float* Ab = p.ws + OFF_A + (size_t)b * 1024;
        for (int idx = tid; idx < 1024; idx += 256) la[idx] = Ab[idx];
        __syncthreads();
        if (tid < 15) {
            const int j = tid;
            float s[15];
            #pragma unroll
            for (int i = 0; i < 15; i++) s[i] = (i == j) ? 0.f : NEG;
            #pragma unroll 4
            for (int t = 0; t < 64; t++) {
                float tv[15];
                #pragma unroll
                for (int i = 0; i < 15; i++) tv[i] = s[i] + la[t*16 + i];
                float nw = lse15(tv);
                #pragma unroll
                for (int i = 14; i > 0; i--) s[i] = s[i-1];
                s[0] = nw;
            }
            float* T0 = p.ws + OFF_T0;
            #pragma unroll
            for (int i = 0; i < 15; i++) T0[b*225 + i*15 + j] = s[i];
        }
    }
    __syncthreads();
    __threadfence();
    if (tid == 0)
        __hip_atomic_fetch_add(&ctr[0], 1u, __ATOMIC_ACQ_REL, __HIP_MEMORY_SCOPE_AGENT);
    if (b >= 16) return;

    // ---- wait for all 256 chunk matrices ----
    if (tid == 0) {
        while (__hip_atomic_load(&ctr[0], __ATOMIC_ACQUIRE, __HIP_MEMORY_SCOPE_AGENT) < 256u)
            __builtin_amdgcn_s_sleep(8);
    }
    __syncthreads();
    __threadfence();

    // ---- D: combine 16 chunk matrices ----
    {
        float* Rm = sm;   // 240, stride 16
        const float* T0 = p.ws + OFF_T0;
        const int e = tid, i2 = e / 15, j2 = e % 15;
        const int c0 = b * 16;
        if (e < 225) Rm[i2*16 + j2] = T0[c0*225 + e];
        __syncthreads();
        for (int t = 1; t < 16; t++) {
            float nw = 0.f;
            if (e < 225) {
                const float* Trow = T0 + (c0 + t)*225 + i2*15;
                float tv[15];
                #pragma unroll
                for (int k = 0; k < 15; k++) tv[k] = Trow[k] + Rm[k*16 + j2];
                nw = lse15(tv);
            }
            __syncthreads();
            if (e < 225) Rm[i2*16 + j2] = nw;
            __syncthreads();
        }
        if (e < 225) p.ws[OFF_R + b*225 + e] = Rm[i2*16 + j2];
    }
    __syncthreads();
    __threadfence();
    if (tid == 0)
        __hip_atomic_fetch_add(&ctr[1], 1u, __ATOMIC_ACQ_REL, __HIP_MEMORY_SCOPE_AGENT);
    if (b != 0) return;

    // ---- wait for 16 combined matrices ----
    if (tid == 0) {
        while (__hip_atomic_load(&ctr[1], __ATOMIC_ACQUIRE, __HIP_MEMORY_SCOPE_AGENT) < 16u)
            __builtin_amdgcn_s_sleep(8);
    }
    __syncthreads();
    __threadfence();

    // ---- E: final combine + indiv + out ----
    {
        float* RA  = sm;           // 16*240
        float* G   = sm + 3840;    // 240
        float* red = sm + 4080;    // 4
        const float* Rg = p.ws + OFF_R;
        for (int idx = tid; idx < 16*225; idx += 256) {
            int t = idx / 225, r = idx % 225;
            RA[t*240 + (r/15)*16 + (r%15)] = Rg[idx];
        }
        __syncthreads();
        const int e = tid, i2 = e / 15, j2 = e % 15;
        if (e < 225) G[i2*16 + j2] = RA[i2*16 + j2];
        __syncthreads();
        for (int t = 1; t < 16; t++) {
            float nw = 0.f;
            if (e < 225) {
                float tv[15];
                #pragma unroll
                for (int k = 0; k < 15; k++) tv[k] = RA[t*240 + i2*16 + k] + G[k*16 + j2];
                nw = lse15(tv);
            }
            __syncthreads();
            if (e < 225) G[i2*16 + j2] = nw;
            __syncthreads();
        }
        const float* gsc = p.ws + OFF_GSC;
        float loc = 0.f;
        for (int s = tid; s < 2048; s += 256) {
            int len = p.lengths[s];
            if (len < 15) loc += gsc[(len-1)*15 + p.tags[s]];
        }
        #pragma unroll
        for (int off = 32; off > 0; off >>= 1) loc += __shfl_down(loc, off);
        if ((tid & 63) == 0) red[tid >> 6] = loc;
        __syncthreads();
        if (tid == 0) {
            float ind = red[0] + red[1] + red[2] + red[3];
            p.out[0] = G[0] - ind;
        }
    }
}

// ================= launcher =================================================
extern "C" void kernel_launch(void* const* d_in, const int* in_sizes, int n_in,
                              void* d_out, int out_size, void* d_ws, size_t ws_size,
                              hipStream_t stream)
{
    Params prm;
    prm.data = (const float*)d_in[0];
    prm.fWih = (const float*)d_in[1];
    prm.fWhh = (const float*)d_in[2];
    prm.fbih = (const float*)d_in[3];
    prm.fbhh = (const float*)d_in[4];
    prm.bWih = (const float*)d_in[5];
    prm.bWhh = (const float*)d_in[6];
    prm.bbih = (const float*)d_in[7];
    prm.bbhh = (const float*)d_in[8];
    prm.h0f  = (const float*)d_in[9];
    prm.c0f  = (const float*)d_in[10];
    prm.h0b  = (const float*)d_in[11];
    prm.c0b  = (const float*)d_in[12];
    prm.Yenc = (const float*)d_in[13];
    prm.Zenc = (const float*)d_in[14];
    prm.VW   = (const float*)d_in[15];
    prm.Vb   = (const float*)d_in[16];
    prm.WW   = (const float*)d_in[17];
    prm.Wb   = (const float*)d_in[18];
    prm.tags    = (const int*)d_in[19];
    prm.lengths = (const int*)d_in[20];
    prm.ws  = (float*)d_ws;
    prm.out = (float*)d_out;

    hipLaunchKernelGGL(kA,   dim3(256, 2), dim3(512), 0, stream, prm);
    hipLaunchKernelGGL(kB,   dim3(480),    dim3(512), 0, stream, prm);
    hipLaunchKernelGGL(kCDE, dim3(256),    dim3(256), 0, stream, prm);
}

// Round 8
// 238.870 us; speedup vs baseline: 1.8200x; 1.0527x over previous
//
#include <hip/hip_runtime.h>

#define NPOS 16384
#define NEG  (-1e30f)

// workspace offsets (floats)
#define OFF_FWDH  0
#define OFF_BWDH  1966080
#define OFF_A     3932160
#define OFF_T0    4194304
#define OFF_R     4251904
#define OFF_GSC   4255504
#define OFF_CTR   4255744   // 1 x u32

struct Params {
    const float *data, *fWih, *fWhh, *fbih, *fbhh, *bWih, *bWhh, *bbih, *bbhh;
    const float *h0f, *c0f, *h0b, *c0b, *Yenc, *Zenc, *VW, *Vb, *WW, *Wb;
    const int *tags, *lengths;
    float *ws; float *out;
};

__device__ __forceinline__ float sigf(float x) {
    return __builtin_amdgcn_rcpf(1.0f + __expf(-x));
}
__device__ __forceinline__ float tanhf_(float x) {
    return 1.0f - 2.0f * __builtin_amdgcn_rcpf(1.0f + __expf(2.0f * x));
}
__device__ __forceinline__ float bflo(unsigned int v) {
    return __builtin_bit_cast(float, v << 16);
}
__device__ __forceinline__ float bfhi(unsigned int v) {
    return __builtin_bit_cast(float, v & 0xffff0000u);
}
__device__ __forceinline__ unsigned short f2bf(float f) {
    unsigned int b = __builtin_bit_cast(unsigned int, f);
    return (unsigned short)((b + 0x8000u) >> 16);
}
__device__ __forceinline__ float lse15(const float* tv) {
    float a0 = fmaxf(tv[0], tv[1]),  a1 = fmaxf(tv[2], tv[3]);
    float a2 = fmaxf(tv[4], tv[5]),  a3 = fmaxf(tv[6], tv[7]);
    float a4 = fmaxf(tv[8], tv[9]),  a5 = fmaxf(tv[10], tv[11]);
    float a6 = fmaxf(tv[12], tv[13]);
    float b0 = fmaxf(a0, a1), b1 = fmaxf(a2, a3), b2 = fmaxf(a4, a5), b3 = fmaxf(a6, tv[14]);
    float mx = fmaxf(fmaxf(b0, b1), fmaxf(b2, b3));
    float e[15];
    #pragma unroll
    for (int i = 0; i < 15; i++) e[i] = __expf(tv[i] - mx);
    float s0 = e[0]+e[1], s1 = e[2]+e[3], s2 = e[4]+e[5], s3 = e[6]+e[7];
    float s4 = e[8]+e[9], s5 = e[10]+e[11], s6 = e[12]+e[13];
    float t0 = s0+s1, t1 = s2+s3, t2 = s4+s5, t3 = s6+e[14];
    return mx + __logf((t0+t1) + (t2+t3));
}

// ================= kA: pack weights (bf16, LDS) + xg + LSTM =================
// grid (256, 2): blockIdx.y = dir. 512 thr = 8 waves; wave wq owns hidden
// units {2wq, 2wq+1} (gates i,f,g,o). lane = position.
__global__ __launch_bounds__(512) void kA(Params p)
{
    __shared__ unsigned int xs2[78*33];   // x rows bf16-pair, stride 33 (10296 B)
    __shared__ unsigned int xgT[32*78];   // xg bf16-pair [gatepair][row] (9984 B)
    __shared__ float hsh[2048];           // h double-buffer (8192 B)
    __shared__ uint4 wqxq[512];           // Wih packed: [k][wq] 8 bf16 (8192 B)
    __shared__ uint4 wqhq[128];           // Whh packed: [m][wq] 8 bf16 (2048 B)
    __shared__ float bq[64];

    const int tid  = threadIdx.x;
    const int lane = tid & 63;
    const int wq   = __builtin_amdgcn_readfirstlane(tid >> 6);
    const int dir  = blockIdx.y;
    const int P0   = blockIdx.x << 6;
    const int dbase = P0 - (dir ? 14 : 0);

    if (blockIdx.x == 0 && dir == 0 && tid == 0) {
        unsigned int* ctr = (unsigned int*)(p.ws + OFF_CTR);
        ctr[0] = 0;
    }

    const float* Wih = dir ? p.bWih : p.fWih;
    const float* Whh = dir ? p.bWhh : p.fWhh;
    const float* bih = dir ? p.bbih : p.fbih;
    const float* bhh = dir ? p.bbhh : p.fbhh;
    const float* h0  = dir ? p.h0b  : p.h0f;
    const float* c0  = dir ? p.c0b  : p.c0f;

    // pack Wih: entry e=(k,pi): pi=w*4+g2 -> gates j0=g2*16+2w, j0+1
    unsigned int* wqx = (unsigned int*)wqxq;
    unsigned int* wqh = (unsigned int*)wqhq;
    for (int e = tid; e < 2048; e += 512) {
        int k = e >> 5, pi = e & 31;
        int w = pi >> 2, g2 = pi & 3;
        int j0 = g2*16 + 2*w;
        wqx[e] = (unsigned int)f2bf(Wih[j0*64 + k])
               | ((unsigned int)f2bf(Wih[(j0+1)*64 + k]) << 16);
    }
    if (tid < 512) {
        int e = tid;
        int m = e >> 5, pi = e & 31;
        int w = pi >> 2, g2 = pi & 3;
        int j0 = g2*16 + 2*w;
        wqh[e] = (unsigned int)f2bf(Whh[j0*16 + m])
               | ((unsigned int)f2bf(Whh[(j0+1)*16 + m]) << 16);
    }
    if (tid < 64) {
        int w = tid >> 3, jj = tid & 7;
        int j = ((jj >> 1) << 4) + 2*w + (jj & 1);
        bq[tid] = bih[j] + bhh[j];
    }
    for (int idx = tid; idx < 78*32; idx += 512) {
        int r = idx >> 5, c = idx & 31;
        int q = dbase + r;
        q = q < 0 ? 0 : (q > NPOS-1 ? NPOS-1 : q);
        float2 x2 = *(const float2*)(p.data + (size_t)q*64 + c*2);
        xs2[r*33 + c] = (unsigned int)f2bf(x2.x) | ((unsigned int)f2bf(x2.y) << 16);
    }
    for (int e = tid; e < 1024; e += 512) hsh[e] = h0[e >> 6];
    __syncthreads();

    // xg = x @ Wih^T + b for rows 0..77 (bf16 weights from LDS, b128 broadcast)
    #pragma unroll
    for (int pass = 0; pass < 2; pass++) {
        int r = pass*64 + lane;
        if (r < 78) {
            float acc[8];
            #pragma unroll
            for (int jj = 0; jj < 8; jj++) acc[jj] = bq[wq*8 + jj];
            #pragma unroll 4
            for (int k2 = 0; k2 < 32; k2++) {
                unsigned int xp = xs2[r*33 + k2];
                float x0 = bflo(xp), x1 = bfhi(xp);
                uint4 w0 = wqxq[(2*k2)*8 + wq];
                uint4 w1 = wqxq[(2*k2+1)*8 + wq];
                unsigned int wa[4] = {w0.x, w0.y, w0.z, w0.w};
                unsigned int wb[4] = {w1.x, w1.y, w1.z, w1.w};
                #pragma unroll
                for (int g2 = 0; g2 < 4; g2++) {
                    acc[2*g2]   = fmaf(bflo(wa[g2]), x0, acc[2*g2]);
                    acc[2*g2]   = fmaf(bflo(wb[g2]), x1, acc[2*g2]);
                    acc[2*g2+1] = fmaf(bfhi(wa[g2]), x0, acc[2*g2+1]);
                    acc[2*g2+1] = fmaf(bfhi(wb[g2]), x1, acc[2*g2+1]);
                }
            }
            #pragma unroll
            for (int g2 = 0; g2 < 4; g2++)
                xgT[(wq*4 + g2)*78 + r] = (unsigned int)f2bf(acc[2*g2])
                                        | ((unsigned int)f2bf(acc[2*g2+1]) << 16);
        }
    }
    float cv0 = c0[wq*2], cv1 = c0[wq*2 + 1];
    unsigned int* outH = (unsigned int*)(p.ws + (dir ? OFF_BWDH : OFF_FWDH));
    __syncthreads();

    int buf = 0;
    for (int d = 0; d < 15; d++) {
        const int row = dir ? (lane + 14 - d) : (lane + d);
        float part[8];
        #pragma unroll
        for (int g2 = 0; g2 < 4; g2++) {
            unsigned int v = xgT[(wq*4 + g2)*78 + row];
            part[2*g2]   = bflo(v);
            part[2*g2+1] = bfhi(v);
        }
        #pragma unroll
        for (int m = 0; m < 16; m++) {
            float hm = hsh[buf*1024 + m*64 + lane];
            uint4 wm = wqhq[m*8 + wq];
            unsigned int wv[4] = {wm.x, wm.y, wm.z, wm.w};
            #pragma unroll
            for (int g2 = 0; g2 < 4; g2++) {
                part[2*g2]   = fmaf(bflo(wv[g2]), hm, part[2*g2]);
                part[2*g2+1] = fmaf(bfhi(wv[g2]), hm, part[2*g2+1]);
            }
        }
        float cn0 = sigf(part[2])*cv0 + sigf(part[0])*tanhf_(part[4]);
        float cn1 = sigf(part[3])*cv1 + sigf(part[1])*tanhf_(part[5]);
        cv0 = cn0; cv1 = cn1;
        float h0v = sigf(part[6])*tanhf_(cn0);
        float h1v = sigf(part[7])*tanhf_(cn1);
        hsh[(buf^1)*1024 + (wq*2)*64 + lane]     = h0v;
        hsh[(buf^1)*1024 + (wq*2 + 1)*64 + lane] = h1v;
        unsigned int pk = (unsigned int)f2bf(h0v) | ((unsigned int)f2bf(h1v) << 16);
        outH[((size_t)d*NPOS + P0 + lane)*8 + wq] = pk;
        __syncthreads();
        buf ^= 1;
    }
}

// ================= kB: scores + A (480 blocks x 512 thr) =====================
__global__ __launch_bounds__(512) void kB(Params p)
{
    __shared__ float yp2[240];
    __shared__ float zbl[240];
    const int tid = threadIdx.x;
    if (tid < 240) {
        int y = tid >> 4, h = tid & 15;
        float acc = 0.f;
        for (int t = 0; t < 32; t++) acc += p.Yenc[y*32 + t] * p.VW[h*68 + 32 + t];
        yp2[tid] = 2.0f * acc;
        float z = p.Vb[h];
        for (int u = 0; u < 4; u++) z += p.Zenc[y*4 + u] * p.VW[h*68 + 64 + u];
        zbl[tid] = z;
    }
    __syncthreads();
    const int g   = blockIdx.x*512 + tid;
    const int pp  = g & (NPOS - 1);
    const int dgl = g >> 14;
    float* ws = p.ws;
    float* A16 = ws + OFF_A;
    if (dgl == 0) A16[pp*16 + 15] = NEG;
    if (pp < dgl) { A16[pp*16 + dgl] = NEG; return; }

    const uint4* fptr = (const uint4*)((const unsigned short*)(ws + OFF_FWDH)
                        + ((size_t)dgl*NPOS + (pp - dgl))*16);
    const uint4* bptr = (const uint4*)((const unsigned short*)(ws + OFF_BWDH)
                        + ((size_t)dgl*NPOS + pp)*16);
    float fb0[16], fb1[16];
    #pragma unroll
    for (int q = 0; q < 2; q++) {
        uint4 v = fptr[q];
        unsigned int wv4[4] = {v.x, v.y, v.z, v.w};
        #pragma unroll
        for (int t = 0; t < 4; t++) {
            fb0[q*8 + 2*t]     = bflo(wv4[t]);
            fb0[q*8 + 2*t + 1] = bfhi(wv4[t]);
        }
        uint4 u = bptr[q];
        unsigned int uu[4] = {u.x, u.y, u.z, u.w};
        #pragma unroll
        for (int t = 0; t < 4; t++) {
            fb1[q*8 + 2*t]     = bflo(uu[t]);
            fb1[q*8 + 2*t + 1] = bfhi(uu[t]);
        }
    }
    float base2[16], w2[16], wsum = 0.f;
    #pragma unroll
    for (int h = 0; h < 16; h++) {
        float acc = zbl[dgl*16 + h];
        #pragma unroll
        for (int m = 0; m < 16; m++) acc = fmaf(p.VW[h*68 + m],      fb0[m], acc);
        #pragma unroll
        for (int m = 0; m < 16; m++) acc = fmaf(p.VW[h*68 + 16 + m], fb1[m], acc);
        base2[h] = acc + acc;
        float w = p.WW[h];
        w2[h] = -2.0f * w;
        wsum += w;
    }
    const float cst = p.Wb[0] + wsum;
    float sc[15];
    #pragma unroll
    for (int y = 0; y < 15; y++) {
        float a = 0.f;
        #pragma unroll
        for (int h = 0; h < 16; h++) {
            float t = __expf(base2[h] + yp2[y*16 + h]);
            a = fmaf(w2[h], __builtin_amdgcn_rcpf(1.0f + t), a);
        }
        sc[y] = cst + a;
    }
    A16[pp*16 + dgl] = lse15(sc);
    if (pp == dgl && pp < 15) {
        float* gsc = ws + OFF_GSC;
        #pragma unroll
        for (int y = 0; y < 15; y++) gsc[pp*15 + y] = sc[y];
    }
}

// ================= kC: 256 chunk transfer matrices (no sync) =================
__global__ __launch_bounds__(256) void kC(Params p)
{
    __shared__ float la[1024];
    const int tid = threadIdx.x;
    const int b   = blockIdx.x;
    const float* Ab = p.ws + OFF_A + (size_t)b * 1024;
    for (int idx = tid; idx < 1024; idx += 256) la[idx] = Ab[idx];
    __syncthreads();
    if (tid >= 15) return;
    const int j = tid;
    float s[15];
    #pragma unroll
    for (int i = 0; i < 15; i++) s[i] = (i == j) ? 0.f : NEG;
    #pragma unroll 4
    for (int t = 0; t < 64; t++) {
        float tv[15];
        #pragma unroll
        for (int i = 0; i < 15; i++) tv[i] = s[i] + la[t*16 + i];
        float nw = lse15(tv);
        #pragma unroll
        for (int i = 14; i > 0; i--) s[i] = s[i-1];
        s[0] = nw;
    }
    float* T0 = p.ws + OFF_T0;
    #pragma unroll
    for (int i = 0; i < 15; i++) T0[b*225 + i*15 + j] = s[i];
}

// ================= kDE: combine 16x16 + last-block final =====================
// 16 blocks x 256 thr. Each block D-combines its 16 chunk matrices -> R[b];
// the last block to finish runs E (final 16-combine + indiv + out).
__global__ __launch_bounds__(256) void kDE(Params p)
{
    __shared__ float sm[4084];
    __shared__ int lastFlag;
    const int tid = threadIdx.x;
    const int b   = blockIdx.x;
    unsigned int* ctr = (unsigned int*)(p.ws + OFF_CTR);

    // ---- D: combine 16 chunk matrices ----
    {
        float* Rm = sm;   // 240, stride 16
        const float* T0 = p.ws + OFF_T0;
        const int e = tid, i2 = e / 15, j2 = e % 15;
        const int c0 = b * 16;
        if (e < 225) Rm[i2*16 + j2] = T0[c0*225 + e];
        __syncthreads();
        for (int t = 1; t < 16; t++) {
            float nw = 0.f;
            if (e < 225) {
                const float* Trow = T0 + (c0 + t)*225 + i2*15;
                float tv[15];
                #pragma unroll
                for (int k = 0; k < 15; k++) tv[k] = Trow[k] + Rm[k*16 + j2];
                nw = lse15(tv);
            }
            __syncthreads();
            if (e < 225) Rm[i2*16 + j2] = nw;
            __syncthreads();
        }
        if (e < 225) p.ws[OFF_R + b*225 + e] = Rm[i2*16 + j2];
    }
    __syncthreads();
    __threadfence();   // release our R[b] writes
    if (tid == 0) {
        unsigned int old = __hip_atomic_fetch_add(&ctr[0], 1u, __ATOMIC_ACQ_REL,
                                                  __HIP_MEMORY_SCOPE_AGENT);
        lastFlag = (old == 15u);
    }
    __syncthreads();
    if (!lastFlag) return;
    __threadfence();   // acquire other blocks' R writes

    // ---- E: final combine + indiv + out ----
    {
        float* RA  = sm;           // 16*240
        float* G   = sm + 3840;    // 240
        float* red = sm + 4080;    // 4
        const float* Rg = p.ws + OFF_R;
        for (int idx = tid; idx < 16*225; idx += 256) {
            int t = idx / 225, r = idx % 225;
            RA[t*240 + (r/15)*16 + (r%15)] = Rg[idx];
        }
        __syncthreads();
        const int e = tid, i2 = e / 15, j2 = e % 15;
        if (e < 225) G[i2*16 + j2] = RA[i2*16 + j2];
        __syncthreads();
        for (int t = 1; t < 16; t++) {
            float nw = 0.f;
            if (e < 225) {
                float tv[15];
                #pragma unroll
                for (int k = 0; k < 15; k++) tv[k] = RA[t*240 + i2*16 + k] + G[k*16 + j2];
                nw = lse15(tv);
            }
            __syncthreads();
            if (e < 225) G[i2*16 + j2] = nw;
            __syncthreads();
        }
        const float* gsc = p.ws + OFF_GSC;
        float loc = 0.f;
        for (int s = tid; s < 2048; s += 256) {
            int len = p.lengths[s];
            if (len < 15) loc += gsc[(len-1)*15 + p.tags[s]];
        }
        #pragma unroll
        for (int off = 32; off > 0; off >>= 1) loc += __shfl_down(loc, off);
        if ((tid & 63) == 0) red[tid >> 6] = loc;
        __syncthreads();
        if (tid == 0) {
            float ind = red[0] + red[1] + red[2] + red[3];
            p.out[0] = G[0] - ind;
        }
    }
}

// ================= launcher =================================================
extern "C" void kernel_launch(void* const* d_in, const int* in_sizes, int n_in,
                              void* d_out, int out_size, void* d_ws, size_t ws_size,
                              hipStream_t stream)
{
    Params prm;
    prm.data = (const float*)d_in[0];
    prm.fWih = (const float*)d_in[1];
    prm.fWhh = (const float*)d_in[2];
    prm.fbih = (const float*)d_in[3];
    prm.fbhh = (const float*)d_in[4];
    prm.bWih = (const float*)d_in[5];
    prm.bWhh = (const float*)d_in[6];
    prm.bbih = (const float*)d_in[7];
    prm.bbhh = (const float*)d_in[8];
    prm.h0f  = (const float*)d_in[9];
    prm.c0f  = (const float*)d_in[10];
    prm.h0b  = (const float*)d_in[11];
    prm.c0b  = (const float*)d_in[12];
    prm.Yenc = (const float*)d_in[13];
    prm.Zenc = (const float*)d_in[14];
    prm.VW   = (const float*)d_in[15];
    prm.Vb   = (const float*)d_in[16];
    prm.WW   = (const float*)d_in[17];
    prm.Wb   = (const float*)d_in[18];
    prm.tags    = (const int*)d_in[19];
    prm.lengths = (const int*)d_in[20];
    prm.ws  = (float*)d_ws;
    prm.out = (float*)d_out;

    hipLaunchKernelGGL(kA,  dim3(256, 2), dim3(512), 0, stream, prm);
    hipLaunchKernelGGL(kB,  dim3(480),    dim3(512), 0, stream, prm);
    hipLaunchKernelGGL(kC,  dim3(256),    dim3(256), 0, stream, prm);
    hipLaunchKernelGGL(kDE, dim3(16),     dim3(256), 0, stream, prm);
}

// Round 10
// 187.283 us; speedup vs baseline: 2.3214x; 1.2754x over previous
//
#include <hip/hip_runtime.h>

#define NPOS 16384
#define NEG  (-1e30f)

// workspace offsets (floats)
#define OFF_FWDH  0
#define OFF_BWDH  1966080
#define OFF_A     3932160
#define OFF_T0    4194304
#define OFF_R     4251904
#define OFF_GSC   4255504
#define OFF_CTR   4255744   // 1 x u32

struct Params {
    const float *data, *fWih, *fWhh, *fbih, *fbhh, *bWih, *bWhh, *bbih, *bbhh;
    const float *h0f, *c0f, *h0b, *c0b, *Yenc, *Zenc, *VW, *Vb, *WW, *Wb;
    const int *tags, *lengths;
    float *ws; float *out;
};

typedef _Float16 half2_t __attribute__((ext_vector_type(2)));

__device__ __forceinline__ half2_t u2h(unsigned int v) {
    return __builtin_bit_cast(half2_t, v);
}
__device__ __forceinline__ unsigned int packh(float a, float b) {
    half2_t h = { (_Float16)a, (_Float16)b };
    return __builtin_bit_cast(unsigned int, h);
}
__device__ __forceinline__ float fdot2_(unsigned int w, unsigned int x, float acc) {
    return __builtin_amdgcn_fdot2(u2h(w), u2h(x), acc, false);
}
__device__ __forceinline__ float sigf(float x) {
    return __builtin_amdgcn_rcpf(1.0f + __expf(-x));
}
__device__ __forceinline__ float tanhf_(float x) {
    return 1.0f - 2.0f * __builtin_amdgcn_rcpf(1.0f + __expf(2.0f * x));
}
__device__ __forceinline__ float lse15(const float* tv) {
    float a0 = fmaxf(tv[0], tv[1]),  a1 = fmaxf(tv[2], tv[3]);
    float a2 = fmaxf(tv[4], tv[5]),  a3 = fmaxf(tv[6], tv[7]);
    float a4 = fmaxf(tv[8], tv[9]),  a5 = fmaxf(tv[10], tv[11]);
    float a6 = fmaxf(tv[12], tv[13]);
    float b0 = fmaxf(a0, a1), b1 = fmaxf(a2, a3), b2 = fmaxf(a4, a5), b3 = fmaxf(a6, tv[14]);
    float mx = fmaxf(fmaxf(b0, b1), fmaxf(b2, b3));
    float e[15];
    #pragma unroll
    for (int i = 0; i < 15; i++) e[i] = __expf(tv[i] - mx);
    float s0 = e[0]+e[1], s1 = e[2]+e[3], s2 = e[4]+e[5], s3 = e[6]+e[7];
    float s4 = e[8]+e[9], s5 = e[10]+e[11], s6 = e[12]+e[13];
    float t0 = s0+s1, t1 = s2+s3, t2 = s4+s5, t3 = s6+e[14];
    return mx + __logf((t0+t1) + (t2+t3));
}

// ================= kA: fp16-dot2 xg + LSTM ==================================
// grid (256,2): blockIdx.y = dir. 512 thr = 8 waves; wave wq owns hidden
// units {2wq, 2wq+1} (gates i,f,g,o). lane = position. All contractions via
// v_dot2_f32_f16 on fp16 pairs (no unpack ops in the hot loops).
__global__ __launch_bounds__(512) void kA(Params p)
{
    __shared__ unsigned int xs2[78*33];   // x fp16-pairs [row][k2], stride 33
    __shared__ float xgT[64*78];          // xg f32 [gate][row]
    __shared__ unsigned int hsh[2*512];   // h fp16-pairs [buf][m2*64+lane]
    __shared__ unsigned int wqx[2048];    // Wih pairs [k2][wq*8+jj]
    __shared__ unsigned int wqh[512];     // Whh pairs [m2][wq*8+jj]
    __shared__ float bq[64];

    const int tid  = threadIdx.x;
    const int lane = tid & 63;
    const int wq   = __builtin_amdgcn_readfirstlane(tid >> 6);
    const int dir  = blockIdx.y;
    const int P0   = blockIdx.x << 6;
    const int dbase = P0 - (dir ? 14 : 0);

    if (blockIdx.x == 0 && dir == 0 && tid == 0)
        ((unsigned int*)(p.ws + OFF_CTR))[0] = 0;

    const float* Wih = dir ? p.bWih : p.fWih;
    const float* Whh = dir ? p.bWhh : p.fWhh;
    const float* bih = dir ? p.bbih : p.fbih;
    const float* bhh = dir ? p.bbhh : p.fbhh;
    const float* h0  = dir ? p.h0b  : p.h0f;
    const float* c0  = dir ? p.c0b  : p.c0f;

    // pack Wih pairs along k: wqx[k2*64 + pi], pi=wq*8+jj <-> gate j
    for (int e = tid; e < 2048; e += 512) {
        int k2 = e >> 6, pi = e & 63;
        int w = pi >> 3, jj = pi & 7;
        int j = ((jj >> 1) << 4) + 2*w + (jj & 1);
        wqx[e] = packh(Wih[j*64 + 2*k2], Wih[j*64 + 2*k2 + 1]);
    }
    if (tid < 512) {
        int m2 = tid >> 6, pi = tid & 63;
        int w = pi >> 3, jj = pi & 7;
        int j = ((jj >> 1) << 4) + 2*w + (jj & 1);
        wqh[tid] = packh(Whh[j*16 + 2*m2], Whh[j*16 + 2*m2 + 1]);
    }
    if (tid < 64) {
        int w = tid >> 3, jj = tid & 7;
        int j = ((jj >> 1) << 4) + 2*w + (jj & 1);
        bq[tid] = bih[j] + bhh[j];
    }
    for (int idx = tid; idx < 78*32; idx += 512) {
        int r = idx >> 5, c = idx & 31;
        int q = dbase + r;
        q = q < 0 ? 0 : (q > NPOS-1 ? NPOS-1 : q);
        float2 x2 = *(const float2*)(p.data + (size_t)q*64 + c*2);
        xs2[r*33 + c] = packh(x2.x, x2.y);
    }
    if (tid < 512) {
        int m2 = tid >> 6;
        hsh[tid] = packh(h0[2*m2], h0[2*m2 + 1]);
    }
    __syncthreads();

    // xg = x @ Wih^T + b, rows 0..77 -> xgT (f32)
    #pragma unroll
    for (int pass = 0; pass < 2; pass++) {
        int r = pass*64 + lane;
        if (r < 78) {
            float acc[8];
            #pragma unroll
            for (int jj = 0; jj < 8; jj++) acc[jj] = bq[wq*8 + jj];
            #pragma unroll 8
            for (int k2 = 0; k2 < 32; k2++) {
                unsigned int xp = xs2[r*33 + k2];
                uint4 w0 = *(const uint4*)&wqx[k2*64 + wq*8];
                uint4 w1 = *(const uint4*)&wqx[k2*64 + wq*8 + 4];
                acc[0] = fdot2_(w0.x, xp, acc[0]);
                acc[1] = fdot2_(w0.y, xp, acc[1]);
                acc[2] = fdot2_(w0.z, xp, acc[2]);
                acc[3] = fdot2_(w0.w, xp, acc[3]);
                acc[4] = fdot2_(w1.x, xp, acc[4]);
                acc[5] = fdot2_(w1.y, xp, acc[5]);
                acc[6] = fdot2_(w1.z, xp, acc[6]);
                acc[7] = fdot2_(w1.w, xp, acc[7]);
            }
            #pragma unroll
            for (int jj = 0; jj < 8; jj++) xgT[(wq*8 + jj)*78 + r] = acc[jj];
        }
    }
    float cv0 = c0[wq*2], cv1 = c0[wq*2 + 1];
    unsigned int* outH = (unsigned int*)(p.ws + (dir ? OFF_BWDH : OFF_FWDH));
    __syncthreads();

    int buf = 0;
    for (int d = 0; d < 15; d++) {
        const int row = dir ? (lane + 14 - d) : (lane + d);
        float part[8];
        #pragma unroll
        for (int jj = 0; jj < 8; jj++) part[jj] = xgT[(wq*8 + jj)*78 + row];
        #pragma unroll
        for (int m2 = 0; m2 < 8; m2++) {
            unsigned int hp = hsh[buf*512 + m2*64 + lane];
            uint4 w0 = *(const uint4*)&wqh[m2*64 + wq*8];
            uint4 w1 = *(const uint4*)&wqh[m2*64 + wq*8 + 4];
            part[0] = fdot2_(w0.x, hp, part[0]);
            part[1] = fdot2_(w0.y, hp, part[1]);
            part[2] = fdot2_(w0.z, hp, part[2]);
            part[3] = fdot2_(w0.w, hp, part[3]);
            part[4] = fdot2_(w1.x, hp, part[4]);
            part[5] = fdot2_(w1.y, hp, part[5]);
            part[6] = fdot2_(w1.z, hp, part[6]);
            part[7] = fdot2_(w1.w, hp, part[7]);
        }
        float cn0 = sigf(part[2])*cv0 + sigf(part[0])*tanhf_(part[4]);
        float cn1 = sigf(part[3])*cv1 + sigf(part[1])*tanhf_(part[5]);
        cv0 = cn0; cv1 = cn1;
        float h0v = sigf(part[6])*tanhf_(cn0);
        float h1v = sigf(part[7])*tanhf_(cn1);
        unsigned int pk = packh(h0v, h1v);
        hsh[(buf^1)*512 + wq*64 + lane] = pk;
        outH[((size_t)d*NPOS + P0 + lane)*8 + wq] = pk;
        __syncthreads();
        buf ^= 1;
    }
}

// ================= kBC: scores + A (in LDS) + chunk DP ======================
// 256 blocks x 1024 thr; block c owns positions P0..P0+63, entries (pl, d).
__global__ __launch_bounds__(1024) void kBC(Params p)
{
    __shared__ float As[64*17];          // A[pl][d], stride 17 (conflict-free)
    __shared__ unsigned int VWh[256];    // VW fp16 pairs [h][j2], j2: 0-7 fwd, 8-15 bwd
    __shared__ float zbl[240];
    __shared__ float EY[240];            // exp(2 * Y_enc @ V2^T)
    const int tid = threadIdx.x;
    const int P0  = blockIdx.x << 6;
    float* ws = p.ws;

    if (tid < 240) {
        int y = tid >> 4, h = tid & 15;
        float acc = 0.f;
        for (int t = 0; t < 32; t++) acc += p.Yenc[y*32 + t] * p.VW[h*68 + 32 + t];
        EY[tid] = __expf(acc + acc);
        float z = p.Vb[h];
        for (int u = 0; u < 4; u++) z += p.Zenc[y*4 + u] * p.VW[h*68 + 64 + u];
        zbl[tid] = z;
    }
    if (tid < 256) {
        int h = tid >> 4, j2 = tid & 15;
        int col = (j2 < 8) ? 2*j2 : 16 + 2*(j2 - 8);
        VWh[tid] = packh(p.VW[h*68 + col], p.VW[h*68 + col + 1]);
    }
    __syncthreads();

    const int pl = tid & 63;
    const int d  = tid >> 6;          // 0..15 (15 = pad)
    const int pp = P0 + pl;
    float Aval = NEG;
    if (d < 15 && pp >= d) {
        const uint4* fptr = (const uint4*)((const unsigned int*)(ws + OFF_FWDH)
                            + ((size_t)d*NPOS + (pp - d))*8);
        const uint4* bptr = (const uint4*)((const unsigned int*)(ws + OFF_BWDH)
                            + ((size_t)d*NPOS + pp)*8);
        uint4 f0 = fptr[0], f1 = fptr[1];
        uint4 b0 = bptr[0], b1 = bptr[1];
        unsigned int fp_[8] = {f0.x, f0.y, f0.z, f0.w, f1.x, f1.y, f1.z, f1.w};
        unsigned int bp_[8] = {b0.x, b0.y, b0.z, b0.w, b1.x, b1.y, b1.z, b1.w};
        float E[16], w2[16], wsum = 0.f;
        #pragma unroll
        for (int h = 0; h < 16; h++) {
            float acc = zbl[d*16 + h];
            uint4 va = *(const uint4*)&VWh[h*16];
            uint4 vb = *(const uint4*)&VWh[h*16 + 4];
            uint4 vc = *(const uint4*)&VWh[h*16 + 8];
            uint4 vd = *(const uint4*)&VWh[h*16 + 12];
            acc = fdot2_(va.x, fp_[0], acc); acc = fdot2_(va.y, fp_[1], acc);
            acc = fdot2_(va.z, fp_[2], acc); acc = fdot2_(va.w, fp_[3], acc);
            acc = fdot2_(vb.x, fp_[4], acc); acc = fdot2_(vb.y, fp_[5], acc);
            acc = fdot2_(vb.z, fp_[6], acc); acc = fdot2_(vb.w, fp_[7], acc);
            acc = fdot2_(vc.x, bp_[0], acc); acc = fdot2_(vc.y, bp_[1], acc);
            acc = fdot2_(vc.z, bp_[2], acc); acc = fdot2_(vc.w, bp_[3], acc);
            acc = fdot2_(vd.x, bp_[4], acc); acc = fdot2_(vd.y, bp_[5], acc);
            acc = fdot2_(vd.z, bp_[6], acc); acc = fdot2_(vd.w, bp_[7], acc);
            E[h] = __expf(acc + acc);
            float w = p.WW[h];
            w2[h] = -2.0f * w;
            wsum += w;
        }
        const float cst = p.Wb[0] + wsum;
        float sc[15];
        #pragma unroll
        for (int y = 0; y < 15; y++) {
            float a = 0.f;
            #pragma unroll
            for (int h = 0; h < 16; h++)
                a = fmaf(w2[h], __builtin_amdgcn_rcpf(1.0f + E[h]*EY[y*16 + h]), a);
            sc[y] = cst + a;
        }
        Aval = lse15(sc);
        if (pp == d && pp < 15) {
            float* gsc = ws + OFF_GSC;
            #pragma unroll
            for (int y = 0; y < 15; y++) gsc[pp*15 + y] = sc[y];
        }
    }
    As[pl*17 + d] = Aval;
    __syncthreads();

    // chunk DP: 64 steps, threads 0..14
    if (tid < 15) {
        const int j = tid;
        float s[15];
        #pragma unroll
        for (int i = 0; i < 15; i++) s[i] = (i == j) ? 0.f : NEG;
        #pragma unroll 4
        for (int t = 0; t < 64; t++) {
            float tv[15];
            #pragma unroll
            for (int i = 0; i < 15; i++) tv[i] = s[i] + As[t*17 + i];
            float nw = lse15(tv);
            #pragma unroll
            for (int i = 14; i > 0; i--) s[i] = s[i-1];
            s[0] = nw;
        }
        float* T0 = ws + OFF_T0;
        #pragma unroll
        for (int i = 0; i < 15; i++) T0[blockIdx.x*225 + i*15 + j] = s[i];
    }
}

// ================= kDE: combine 16x16 + last-block final =====================
__global__ __launch_bounds__(256) void kDE(Params p)
{
    __shared__ float sm[4084];
    __shared__ int lastFlag;
    const int tid = threadIdx.x;
    const int b   = blockIdx.x;
    unsigned int* ctr = (unsigned int*)(p.ws + OFF_CTR);

    {
        float* Rm = sm;   // 240, stride 16
        const float* T0 = p.ws + OFF_T0;
        const int e = tid, i2 = e / 15, j2 = e % 15;
        const int c0 = b * 16;
        if (e < 225) Rm[i2*16 + j2] = T0[c0*225 + e];
        __syncthreads();
        for (int t = 1; t < 16; t++) {
            float nw = 0.f;
            if (e < 225) {
                const float* Trow = T0 + (c0 + t)*225 + i2*15;
                float tv[15];
                #pragma unroll
                for (int k = 0; k < 15; k++) tv[k] = Trow[k] + Rm[k*16 + j2];
                nw = lse15(tv);
            }
            __syncthreads();
            if (e < 225) Rm[i2*16 + j2] = nw;
            __syncthreads();
        }
        if (e < 225) p.ws[OFF_R + b*225 + e] = Rm[i2*16 + j2];
    }
    __syncthreads();
    __threadfence();
    if (tid == 0) {
        unsigned int old = __hip_atomic_fetch_add(&ctr[0], 1u, __ATOMIC_ACQ_REL,
                                                  __HIP_MEMORY_SCOPE_AGENT);
        lastFlag = (old == 15u);
    }
    __syncthreads();
    if (!lastFlag) return;
    __threadfence();

    {
        float* RA  = sm;           // 16*240
        float* G   = sm + 3840;    // 240
        float* red = sm + 4080;    // 4
        const float* Rg = p.ws + OFF_R;
        for (int idx = tid; idx < 16*225; idx += 256) {
            int t = idx / 225, r = idx % 225;
            RA[t*240 + (r/15)*16 + (r%15)] = Rg[idx];
        }
        __syncthreads();
        const int e = tid, i2 = e / 15, j2 = e % 15;
        if (e < 225) G[i2*16 + j2] = RA[i2*16 + j2];
        __syncthreads();
        for (int t = 1; t < 16; t++) {
            float nw = 0.f;
            if (e < 225) {
                float tv[15];
                #pragma unroll
                for (int k = 0; k < 15; k++) tv[k] = RA[t*240 + i2*16 + k] + G[k*16 + j2];
                nw = lse15(tv);
            }
            __syncthreads();
            if (e < 225) G[i2*16 + j2] = nw;
            __syncthreads();
        }
        const float* gsc = p.ws + OFF_GSC;
        float loc = 0.f;
        for (int s = tid; s < 2048; s += 256) {
            int len = p.lengths[s];
            if (len < 15) loc += gsc[(len-1)*15 + p.tags[s]];
        }
        #pragma unroll
        for (int off = 32; off > 0; off >>= 1) loc += __shfl_down(loc, off);
        if ((tid & 63) == 0) red[tid >> 6] = loc;
        __syncthreads();
        if (tid == 0) {
            float ind = red[0] + red[1] + red[2] + red[3];
            p.out[0] = G[0] - ind;
        }
    }
}

// ================= launcher =================================================
extern "C" void kernel_launch(void* const* d_in, const int* in_sizes, int n_in,
                              void* d_out, int out_size, void* d_ws, size_t ws_size,
                              hipStream_t stream)
{
    Params prm;
    prm.data = (const float*)d_in[0];
    prm.fWih = (const float*)d_in[1];
    prm.fWhh = (const float*)d_in[2];
    prm.fbih = (const float*)d_in[3];
    prm.fbhh = (const float*)d_in[4];
    prm.bWih = (const float*)d_in[5];
    prm.bWhh = (const float*)d_in[6];
    prm.bbih = (const float*)d_in[7];
    prm.bbhh = (const float*)d_in[8];
    prm.h0f  = (const float*)d_in[9];
    prm.c0f  = (const float*)d_in[10];
    prm.h0b  = (const float*)d_in[11];
    prm.c0b  = (const float*)d_in[12];
    prm.Yenc = (const float*)d_in[13];
    prm.Zenc = (const float*)d_in[14];
    prm.VW   = (const float*)d_in[15];
    prm.Vb   = (const float*)d_in[16];
    prm.WW   = (const float*)d_in[17];
    prm.Wb   = (const float*)d_in[18];
    prm.tags    = (const int*)d_in[19];
    prm.lengths = (const int*)d_in[20];
    prm.ws  = (float*)d_ws;
    prm.out = (float*)d_out;

    hipLaunchKernelGGL(kA,  dim3(256, 2), dim3(512),  0, stream, prm);
    hipLaunchKernelGGL(kBC, dim3(256),    dim3(1024), 0, stream, prm);
    hipLaunchKernelGGL(kDE, dim3(16),     dim3(256),  0, stream, prm);
}